// Round 1
// baseline (818.580 us; speedup 1.0000x reference)
//
#include <hip/hip_runtime.h>

#define NN 50000
#define NE 800000
#define NF 64
#define NL 3

// deg[i] = 1.0 (self loop)
__global__ void deg_init_k(float* __restrict__ deg, int n) {
    int i = blockIdx.x * blockDim.x + threadIdx.x;
    if (i < n) deg[i] = 1.0f;
}

// deg[dst[e]] += 1
__global__ void deg_scatter_k(const int* __restrict__ dst, float* __restrict__ deg, int e) {
    int i = blockIdx.x * blockDim.x + threadIdx.x;
    if (i < e) atomicAdd(&deg[dst[i]], 1.0f);
}

// deg -> 1/deg  (deg >= 1 always, thanks to self loops)
__global__ void deg_inv_k(float* __restrict__ deg, int n) {
    int i = blockIdx.x * blockDim.x + threadIdx.x;
    if (i < n) deg[i] = 1.0f / deg[i];
}

// agg[i][:] = x[i][:]   (self-loop contribution; also initializes poisoned ws)
__global__ void agg_init_k(const float4* __restrict__ x, float4* __restrict__ agg, int n4) {
    int i = blockIdx.x * blockDim.x + threadIdx.x;
    if (i < n4) agg[i] = x[i];
}

// one wave per edge, lane = feature: agg[dst][f] += x[src][f]
__global__ void scatter_k(const int* __restrict__ src, const int* __restrict__ dst,
                          const float* __restrict__ x, float* __restrict__ agg, int e) {
    int gid = blockIdx.x * blockDim.x + threadIdx.x;
    int ei = gid >> 6;
    if (ei >= e) return;
    int f = gid & 63;
    int s = src[ei];
    int d = dst[ei];
    atomicAdd(&agg[d * NF + f], x[s * NF + f]);
}

// out[i][j] = sum_k (agg[i][k]*invdeg[i]) * W[j][k]
// wave per row; W in LDS padded [64][65] -> bank (j+k)%32, 2 lanes/bank (free)
__global__ void linear_k(const float* __restrict__ agg, const float* __restrict__ invdeg,
                         const float* __restrict__ W, float* __restrict__ out, int n) {
    __shared__ float ws[NF][NF + 1];
    int tid = threadIdx.x;
    #pragma unroll
    for (int i = tid; i < NF * NF; i += 256) {
        ws[i >> 6][i & 63] = W[i];   // ws[o][k] = W[o][k]; consecutive tid -> consecutive k: conflict-free
    }
    __syncthreads();
    int lane = tid & 63;
    int row = blockIdx.x * 4 + (tid >> 6);
    if (row >= n) return;
    float a = agg[row * NF + lane] * invdeg[row];
    float acc = 0.0f;
    #pragma unroll
    for (int k = 0; k < NF; ++k) {
        acc = fmaf(__shfl(a, k, 64), ws[lane][k], acc);
    }
    out[row * NF + lane] = acc;
}

extern "C" void kernel_launch(void* const* d_in, const int* in_sizes, int n_in,
                              void* d_out, int out_size, void* d_ws, size_t ws_size,
                              hipStream_t stream) {
    const float* x_in    = (const float*)d_in[0];
    const int*   edge    = (const int*)d_in[1];     // [2][NE]: src = edge, dst = edge + NE
    const float* weights = (const float*)d_in[2];   // [NL][NF][NF]
    float* out = (float*)d_out;

    const int* e_src = edge;
    const int* e_dst = edge + NE;

    // ws layout: deg/invdeg [NN floats, padded to 256KB], agg [NN*NF floats]
    float* deg = (float*)d_ws;
    float* agg = (float*)d_ws + (256 * 1024 / 4);

    // ---- degree ----
    deg_init_k<<<(NN + 255) / 256, 256, 0, stream>>>(deg, NN);
    deg_scatter_k<<<(NE + 255) / 256, 256, 0, stream>>>(e_dst, deg, NE);
    deg_inv_k<<<(NN + 255) / 256, 256, 0, stream>>>(deg, NN);

    // ---- layers ----
    const int n4 = NN * NF / 4;                      // float4 count
    const long long sc_threads = (long long)NE * NF; // 51.2M
    const int sc_blocks = (int)((sc_threads + 255) / 256);

    for (int l = 0; l < NL; ++l) {
        const float* x_cur = (l == 0) ? x_in : out;  // ping through d_out
        agg_init_k<<<(n4 + 255) / 256, 256, 0, stream>>>((const float4*)x_cur, (float4*)agg, n4);
        scatter_k<<<sc_blocks, 256, 0, stream>>>(e_src, e_dst, x_cur, agg, NE);
        linear_k<<<(NN + 3) / 4, 256, 0, stream>>>(agg, deg, weights + l * NF * NF, out, NN);
    }
}

// Round 4
// 434.657 us; speedup vs baseline: 1.8833x; 1.8833x over previous
//
#include <hip/hip_runtime.h>

#define NN 50000
#define NE 800000
#define NF 64
#define NL 3

// ---------- CSR build ----------

__global__ void zero_k(int* __restrict__ p, int n) {
    int i = blockIdx.x * blockDim.x + threadIdx.x;
    if (i < n) p[i] = 0;
}

__global__ void count_k(const int* __restrict__ dst, int* __restrict__ cnt, int e) {
    int i = blockIdx.x * blockDim.x + threadIdx.x;
    if (i < e) atomicAdd(&cnt[dst[i]], 1);
}

// single-workgroup exclusive scan (1024 thr): rowptr/fill = excl prefix, invdeg = 1/(cnt+1)
__global__ void scan_k(const int* __restrict__ cnt, int* __restrict__ rowptr,
                       int* __restrict__ fill, float* __restrict__ invdeg, int n) {
    __shared__ int wsum[16];
    int tid = threadIdx.x;
    int lane = tid & 63, wid = tid >> 6;
    int carry = 0;
    for (int base = 0; base < n; base += 1024) {
        int i = base + tid;
        int v = (i < n) ? cnt[i] : 0;
        int s = v;
        #pragma unroll
        for (int off = 1; off < 64; off <<= 1) {
            int t = __shfl_up(s, off, 64);
            if (lane >= off) s += t;
        }
        if (lane == 63) wsum[wid] = s;          // wave inclusive totals
        __syncthreads();
        if (tid < 64) {                          // one wave scans the 16 wave-sums
            int w = (lane < 16) ? wsum[lane] : 0;
            #pragma unroll
            for (int off = 1; off < 16; off <<= 1) {
                int t = __shfl_up(w, off, 64);
                if (lane >= off) w += t;
            }
            if (lane < 16) wsum[lane] = w;
        }
        __syncthreads();
        int woff = (wid > 0) ? wsum[wid - 1] : 0;
        int incl = s + woff + carry;
        if (i < n) {
            int excl = incl - v;
            rowptr[i] = excl;
            fill[i]   = excl;
            invdeg[i] = 1.0f / (float)(v + 1);   // +1 self loop
        }
        int total = wsum[15];
        __syncthreads();                         // protect wsum before next iter overwrites
        carry += total;
    }
    if (tid == 0) rowptr[n] = carry;
}

__global__ void fill_k(const int* __restrict__ src, const int* __restrict__ dst,
                       int* __restrict__ fill, int* __restrict__ col, int e) {
    int i = blockIdx.x * blockDim.x + threadIdx.x;
    if (i < e) {
        int p = atomicAdd(&fill[dst[i]], 1);
        col[p] = src[i];
    }
}

// ---------- fused gather-mean + linear ----------
// wave per node, lane per feature: acc = x[row] + sum_{e} x[col[e]]; a = acc*invdeg;
// out[row][j] = sum_k a_k * W[j][k]  (W row-major [out][in], staged in LDS)
__global__ __launch_bounds__(256) void layer_k(const float* __restrict__ x,
                                               const int* __restrict__ rowptr,
                                               const int* __restrict__ col,
                                               const float* __restrict__ invdeg,
                                               const float* __restrict__ W,
                                               float* __restrict__ out, int n) {
    __shared__ float ws[NF][NF + 1];             // +1 pad: ws[lane][k] bank=(lane+k)%32, 2-way = free
    int tid = threadIdx.x;
    #pragma unroll
    for (int i = tid; i < NF * NF; i += 256) ws[i >> 6][i & 63] = W[i];
    __syncthreads();

    int lane = tid & 63;
    int row = blockIdx.x * 4 + (tid >> 6);
    if (row >= n) return;

    int beg = rowptr[row], end = rowptr[row + 1];
    float acc0 = x[row * NF + lane];             // self loop
    float acc1 = 0.0f;
    int e = beg;
    for (; e + 3 < end; e += 4) {                // 4 gathers in flight, 2 acc chains
        int s0 = col[e], s1 = col[e + 1], s2 = col[e + 2], s3 = col[e + 3];
        float v0 = x[s0 * NF + lane];
        float v1 = x[s1 * NF + lane];
        float v2 = x[s2 * NF + lane];
        float v3 = x[s3 * NF + lane];
        acc0 += v0 + v2;
        acc1 += v1 + v3;
    }
    for (; e < end; ++e) acc0 += x[col[e] * NF + lane];
    float a = (acc0 + acc1) * invdeg[row];

    float o = 0.0f;
    #pragma unroll
    for (int k = 0; k < NF; ++k) o = fmaf(__shfl(a, k, 64), ws[lane][k], o);
    out[row * NF + lane] = o;
}

extern "C" void kernel_launch(void* const* d_in, const int* in_sizes, int n_in,
                              void* d_out, int out_size, void* d_ws, size_t ws_size,
                              hipStream_t stream) {
    const float* x_in    = (const float*)d_in[0];
    const int*   edge    = (const int*)d_in[1];     // [2][NE]
    const float* weights = (const float*)d_in[2];   // [NL][NF][NF]
    float* out = (float*)d_out;

    const int* e_src = edge;
    const int* e_dst = edge + NE;

    // ws layout (256KB-aligned slots)
    char* w = (char*)d_ws;
    int*   cnt    = (int*)(w);                      // [0, 256K)
    int*   rowptr = (int*)(w + (256 << 10));        // [256K, 512K)  NN+1 ints
    int*   fill   = (int*)(w + (512 << 10));        // [512K, 768K)
    float* invdeg = (float*)(w + (768 << 10));      // [768K, 1M)
    int*   col    = (int*)(w + (1 << 20));          // [1M, 1M+3.2M)
    float* bufA   = (float*)(w + (8 << 20));        // [8M, 8M+12.8M)

    // ---- CSR build (every call; ws is re-poisoned) ----
    zero_k <<<(NN + 255) / 256, 256, 0, stream>>>(cnt, NN);
    count_k<<<(NE + 255) / 256, 256, 0, stream>>>(e_dst, cnt, NE);
    scan_k <<<1, 1024, 0, stream>>>(cnt, rowptr, fill, invdeg, NN);
    fill_k <<<(NE + 255) / 256, 256, 0, stream>>>(e_src, e_dst, fill, col, NE);

    // ---- layers: xin -> A -> out -> A, then copy A -> out ----
    const int blocks = (NN + 3) / 4;
    layer_k<<<blocks, 256, 0, stream>>>(x_in, rowptr, col, invdeg, weights + 0 * NF * NF, bufA, NN);
    layer_k<<<blocks, 256, 0, stream>>>(bufA, rowptr, col, invdeg, weights + 1 * NF * NF, out,  NN);
    layer_k<<<blocks, 256, 0, stream>>>(out,  rowptr, col, invdeg, weights + 2 * NF * NF, bufA, NN);
    hipMemcpyAsync(out, bufA, (size_t)NN * NF * sizeof(float), hipMemcpyDeviceToDevice, stream);
}

// Round 5
// 268.568 us; speedup vs baseline: 3.0479x; 1.6184x over previous
//
#include <hip/hip_runtime.h>

#define NN 50000
#define NE 800000
#define NF 64
#define NL 3

typedef unsigned int uint;
typedef unsigned short ushort;
using short8 = __attribute__((ext_vector_type(8))) short;
using f32x4  = __attribute__((ext_vector_type(4))) float;

__device__ inline ushort f2bf(float f) {              // RNE truncate to bf16
    uint u = __float_as_uint(f);
    u += 0x7fffu + ((u >> 16) & 1u);
    return (ushort)(u >> 16);
}
__device__ inline float bf2f(ushort h) { return __uint_as_float(((uint)h) << 16); }

// ---------- build padded buckets: deg[n], colp[n][64] ----------

__global__ void zero_k(int* __restrict__ p, int n) {
    int i = blockIdx.x * blockDim.x + threadIdx.x;
    if (i < n) p[i] = 0;
}

__global__ void fill_k(const int* __restrict__ src, const int* __restrict__ dst,
                       int* __restrict__ deg, int* __restrict__ colp, int e) {
    int i = blockIdx.x * blockDim.x + threadIdx.x;
    if (i < e) {
        int d = dst[i];
        int slot = atomicAdd(&deg[d], 1);
        if (slot < 64) colp[(size_t)d * 64 + slot] = src[i];   // P(deg>64)~1e-15: guarded
    }
}

// ---------- gather-mean: agg[row] = (x[row] + sum_e x[col]) / (deg+1) ----------
// wave per node, lane per feature. NO LDS, NO shfl — DS pipe stays idle.
__global__ __launch_bounds__(256) void gather_k(const float* __restrict__ x,
                                                const int* __restrict__ deg,
                                                const int* __restrict__ colp,
                                                float* __restrict__ agg, int n) {
    int tid = threadIdx.x;
    int lane = tid & 63;
    int row = blockIdx.x * 4 + (tid >> 6);
    if (row >= n) return;
    int dg = deg[row];
    float invd = 1.0f / (float)(dg + 1);
    const int* cp = colp + (size_t)row * 64;
    float acc0 = x[(size_t)row * NF + lane];   // self loop
    float acc1 = 0.f, acc2 = 0.f, acc3 = 0.f;
    int e = 0;
    for (; e + 8 <= dg; e += 8) {              // 8 gathers in flight, 4 chains
        int4 ca = ((const int4*)cp)[(e >> 2)];
        int4 cb = ((const int4*)cp)[(e >> 2) + 1];
        float v0 = x[(size_t)ca.x * NF + lane];
        float v1 = x[(size_t)ca.y * NF + lane];
        float v2 = x[(size_t)ca.z * NF + lane];
        float v3 = x[(size_t)ca.w * NF + lane];
        float v4 = x[(size_t)cb.x * NF + lane];
        float v5 = x[(size_t)cb.y * NF + lane];
        float v6 = x[(size_t)cb.z * NF + lane];
        float v7 = x[(size_t)cb.w * NF + lane];
        acc0 += v0; acc1 += v1; acc2 += v2; acc3 += v3;
        acc0 += v4; acc1 += v5; acc2 += v6; acc3 += v7;
    }
    for (; e < dg; ++e)
        acc0 += x[(size_t)cp[e] * NF + lane];
    agg[(size_t)row * NF + lane] = (acc0 + acc1 + acc2 + acc3) * invd;
}

// ---------- GEMM: O[n x 64] = A[n x 64] @ W^T (W row-major [out][in]) ----------
// mfma_f32_16x16x32_bf16, split-bf16 3 terms for fp32-grade accuracy.
// Layouts (m89-verified family): A: row=lane&15, k=(lane>>4)*8+i
//                                B: col=lane&15, k=(lane>>4)*8+i
//                                C: col=lane&15, row=(lane>>4)*4+reg
__global__ __launch_bounds__(256) void gemm_k(const float* __restrict__ A,
                                              const float* __restrict__ Wg,
                                              float* __restrict__ O, int n) {
    int tid = threadIdx.x;
    int lane = tid & 63, w = tid >> 6;
    int m = lane & 15, g = lane >> 4;
    int ko = g * 8;
    int row0 = blockIdx.x * 64;

    int arow = row0 + w * 16 + m;
    if (arow > n - 1) arow = n - 1;            // tail: clamp loads, mask stores
    const float* ar = A + (size_t)arow * NF;

    float af[16];
    *(float4*)(af + 0)  = *(const float4*)(ar + ko);
    *(float4*)(af + 4)  = *(const float4*)(ar + ko + 4);
    *(float4*)(af + 8)  = *(const float4*)(ar + 32 + ko);
    *(float4*)(af + 12) = *(const float4*)(ar + 32 + ko + 4);

    short8 ah0, al0, ah1, al1;
    #pragma unroll
    for (int i = 0; i < 8; ++i) {
        ushort h = f2bf(af[i]);
        ah0[i] = (short)h; al0[i] = (short)f2bf(af[i] - bf2f(h));
        ushort h2 = f2bf(af[8 + i]);
        ah1[i] = (short)h2; al1[i] = (short)f2bf(af[8 + i] - bf2f(h2));
    }

    f32x4 acc[4];
    #pragma unroll
    for (int t = 0; t < 4; ++t) {
        const float* wr = Wg + (size_t)(t * 16 + m) * NF;   // B col n = t*16+m -> W row n
        float wf[16];
        *(float4*)(wf + 0)  = *(const float4*)(wr + ko);
        *(float4*)(wf + 4)  = *(const float4*)(wr + ko + 4);
        *(float4*)(wf + 8)  = *(const float4*)(wr + 32 + ko);
        *(float4*)(wf + 12) = *(const float4*)(wr + 32 + ko + 4);
        short8 bh0, bl0, bh1, bl1;
        #pragma unroll
        for (int i = 0; i < 8; ++i) {
            ushort h = f2bf(wf[i]);
            bh0[i] = (short)h; bl0[i] = (short)f2bf(wf[i] - bf2f(h));
            ushort h2 = f2bf(wf[8 + i]);
            bh1[i] = (short)h2; bl1[i] = (short)f2bf(wf[8 + i] - bf2f(h2));
        }
        f32x4 c = {0.f, 0.f, 0.f, 0.f};
        c = __builtin_amdgcn_mfma_f32_16x16x32_bf16(ah0, bh0, c, 0, 0, 0);
        c = __builtin_amdgcn_mfma_f32_16x16x32_bf16(ah1, bh1, c, 0, 0, 0);
        c = __builtin_amdgcn_mfma_f32_16x16x32_bf16(al0, bh0, c, 0, 0, 0);
        c = __builtin_amdgcn_mfma_f32_16x16x32_bf16(al1, bh1, c, 0, 0, 0);
        c = __builtin_amdgcn_mfma_f32_16x16x32_bf16(ah0, bl0, c, 0, 0, 0);
        c = __builtin_amdgcn_mfma_f32_16x16x32_bf16(ah1, bl1, c, 0, 0, 0);
        acc[t] = c;
    }

    #pragma unroll
    for (int t = 0; t < 4; ++t) {
        #pragma unroll
        for (int r = 0; r < 4; ++r) {
            int orow = row0 + w * 16 + g * 4 + r;
            if (orow < n) O[(size_t)orow * NF + t * 16 + m] = acc[t][r];
        }
    }
}

extern "C" void kernel_launch(void* const* d_in, const int* in_sizes, int n_in,
                              void* d_out, int out_size, void* d_ws, size_t ws_size,
                              hipStream_t stream) {
    const float* x_in = (const float*)d_in[0];
    const int*   edge = (const int*)d_in[1];      // [2][NE]
    const float* Wg   = (const float*)d_in[2];    // [NL][64][64]
    float* out = (float*)d_out;

    // ws: deg [0,256K) | colp [256K, 256K+12.8M) | agg [14M, 14M+12.8M)  ~= 26.8 MB
    int*   deg  = (int*)d_ws;
    int*   colp = (int*)((char*)d_ws + (256 << 10));
    float* agg  = (float*)((char*)d_ws + (14 << 20));

    zero_k<<<(NN + 255) / 256, 256, 0, stream>>>(deg, NN);
    fill_k<<<(NE + 255) / 256, 256, 0, stream>>>(edge, edge + NE, deg, colp, NE);

    const int gb = (NN + 3) / 4;        // gather blocks
    const int mb = (NN + 63) / 64;      // gemm blocks

    gather_k<<<gb, 256, 0, stream>>>(x_in, deg, colp, agg, NN);
    gemm_k  <<<mb, 256, 0, stream>>>(agg, Wg + 0 * NF * NF, out, NN);
    gather_k<<<gb, 256, 0, stream>>>(out, deg, colp, agg, NN);
    gemm_k  <<<mb, 256, 0, stream>>>(agg, Wg + 1 * NF * NF, out, NN);
    gather_k<<<gb, 256, 0, stream>>>(out, deg, colp, agg, NN);
    gemm_k  <<<mb, 256, 0, stream>>>(agg, Wg + 2 * NF * NF, out, NN);
}